// Round 3
// baseline (453.435 us; speedup 1.0000x reference)
//
#include <hip/hip_runtime.h>
#include <stdint.h>

#define N_BATCH 32
#define CHN     256
#define HW      56
#define HP      58
#define HPT     7

// xpad layout (uint4 "cells" of 4 u32 = 128 channel-bits):
//   cell(n, hp, h, wp) = ((n*58 + hp)*2 + h)*58 + wp,  h = channel-half (0:c0-127, 1:c128-255)
#define XPAD_CELLS (N_BATCH * HP * 2 * HP)   // 215,296 cells
#define XPAD_U32   (XPAD_CELLS * 4)          // 861,184 u32

__device__ inline void gload_lds16(const void* g, void* l) {
    __builtin_amdgcn_global_load_lds((const __attribute__((address_space(1))) uint32_t*)g,
                                     (__attribute__((address_space(3))) uint32_t*)l, 16, 0, 0);
}

// ---------------- weight binarization via ballot ----------------------------
// block = 256 threads (4 waves) per output channel o; thread t = input channel.
__global__ __launch_bounds__(256) void binw_kernel(const float* __restrict__ wsrc,
                                                   uint32_t* __restrict__ wbits,
                                                   int* __restrict__ wpop) {
    __shared__ int part[9][4];
    int o = blockIdx.x;
    int t = threadIdx.x;
    int lane = t & 63, wv = t >> 6;
    const float* p = wsrc + ((size_t)o * 256 + t) * 9;
    float v[9];
#pragma unroll
    for (int tap = 0; tap < 9; tap++) v[tap] = p[tap];
#pragma unroll
    for (int tap = 0; tap < 9; tap++) {
        unsigned long long m = __ballot(v[tap] > 0.0f);
        if (lane == 0) {
            wbits[(size_t)(o * 9 + tap) * 8 + 2 * wv]     = (uint32_t)m;
            wbits[(size_t)(o * 9 + tap) * 8 + 2 * wv + 1] = (uint32_t)(m >> 32);
            part[tap][wv] = __builtin_popcountll(m);
        }
    }
    __syncthreads();
    if (t < 9) wpop[o * 9 + t] = part[t][0] + part[t][1] + part[t][2] + part[t][3];
}

// ---------------- x binarization ------------------------------------------
// thread = (quad of 4 pixels, one 32-channel word k). 784 blocks x 256.
__global__ __launch_bounds__(256) void binx_kernel(const float* __restrict__ x,
                                                   uint32_t* __restrict__ xpad) {
    int t    = threadIdx.x;
    int lane = t & 63;
    int fw   = blockIdx.x * 4 + (t >> 6);   // flat wave id, 0..3135
    int k    = fw & 7;                      // word index (channels 32k..32k+31)
    int q    = (fw >> 3) * 64 + lane;       // quad id, 0..25087
    int n    = q / 784;
    int pq   = q - n * 784;                 // quad within plane (3136/4)

    const float4* src = (const float4*)x + ((size_t)(n * 256 + k * 32)) * 784 + pq;
    uint32_t b0 = 0, b1 = 0, b2 = 0, b3 = 0;
#pragma unroll
    for (int cc = 0; cc < 32; cc++) {
        float4 v = src[(size_t)cc * 784];
        b0 |= (v.x > 0.0f ? 1u : 0u) << cc;
        b1 |= (v.y > 0.0f ? 1u : 0u) << cc;
        b2 |= (v.z > 0.0f ? 1u : 0u) << cc;
        b3 |= (v.w > 0.0f ? 1u : 0u) << cc;
    }
    int h  = pq / 14;                       // image row 0..55
    int wq = pq - h * 14;
    int w0 = wq * 4;                        // image col of first pixel
    uint32_t cell = ((uint32_t)(n * HP + h + 1) * 2 + (k >> 2)) * HP + (w0 + 1);
    uint32_t* dst = xpad + (size_t)cell * 4 + (k & 3);
    dst[0] = b0; dst[4] = b1; dst[8] = b2; dst[12] = b3;   // pixel stride = 1 cell
}

// ---------------- binary conv ----------------------------------------------
// grid (8 strips, 32 o-groups of 8, 32 n), block 256 = 4 waves.
// Wave wv computes o_a = og*8+2wv (W in SGPRs) and o_b = +1 (W in VGPRs via LDS).
// X strip (9 padded rows x 58 px x 2 halves = 1044 cells) staged in LDS once.
__global__ __launch_bounds__(256) void conv_kernel(const uint32_t* __restrict__ xpad,
                                                   const uint32_t* __restrict__ wbits,
                                                   const int* __restrict__ wpop,
                                                   float* __restrict__ out) {
    __shared__ uint4 sx[1056];      // 16.9 KB (1044 staged + slack)
    __shared__ uint4 sw4[144];      // 8 o * 72 u32

    int t    = threadIdx.x;
    int lane = t & 63;
    int wv   = __builtin_amdgcn_readfirstlane(t >> 6);
    int strip = blockIdx.x;
    int og    = blockIdx.y;
    int n     = blockIdx.z;
    int hb    = strip * HPT;

    // stage the 8 o's weight bits (2304 B)
    const uint4* wg4 = (const uint4*)(wbits + (size_t)og * 8 * 72);
    if (t < 144) sw4[t] = wg4[t];

    // stage X strip: 1044 cells contiguous in global; 17 chunks of 64 cells,
    // tail chunk predicated so we never touch cells >= 1044.
    const uint4* xg = (const uint4*)xpad + (size_t)(n * HP + hb) * (2 * HP);
    for (int i = wv; i < 17; i += 4) {
        if (i * 64 + lane < 1044)
            gload_lds16(xg + i * 64 + lane, (void*)((uint4*)sx + i * 64));
    }
    __syncthreads();

    // weights: o_a uniform -> s_load; o_b via LDS -> VGPR
    const uint32_t* wa = wbits + (size_t)(og * 8 + 2 * wv) * 72;
    uint32_t WA[72];
#pragma unroll
    for (int i = 0; i < 72; i++) WA[i] = wa[i];
    uint4 WB[18];
#pragma unroll
    for (int i = 0; i < 18; i++) WB[i] = sw4[(2 * wv + 1) * 18 + i];
    const uint32_t* WBu = (const uint32_t*)WB;

    int acca[HPT], accb[HPT];
#pragma unroll
    for (int r = 0; r < HPT; r++) { acca[r] = 0; accb[r] = 0; }

    const char* sxb = (const char*)sx + lane * 16;   // one addr reg, imm offsets
#pragma unroll
    for (int j = 0; j < HPT + 2; j++) {
#pragma unroll
        for (int h = 0; h < 2; h++) {
            uint4 X0 = *(const uint4*)(sxb + ((j * 2 + h) * HP + 0) * 16);
            uint4 X1 = *(const uint4*)(sxb + ((j * 2 + h) * HP + 1) * 16);
            uint4 X2 = *(const uint4*)(sxb + ((j * 2 + h) * HP + 2) * 16);
#pragma unroll
            for (int dh = 0; dh < 3; dh++) {
                int r = j - dh;
                if (r >= 0 && r < HPT) {
#pragma unroll
                    for (int dw = 0; dw < 3; dw++) {
                        uint4 X = (dw == 0) ? X0 : (dw == 1) ? X1 : X2;
                        int ta = (dh * 3 + dw) * 8 + h * 4;
                        acca[r] += __builtin_popcount(X.x ^ WA[ta + 0])
                                 + __builtin_popcount(X.y ^ WA[ta + 1])
                                 + __builtin_popcount(X.z ^ WA[ta + 2])
                                 + __builtin_popcount(X.w ^ WA[ta + 3]);
                        accb[r] += __builtin_popcount(X.x ^ WBu[ta + 0])
                                 + __builtin_popcount(X.y ^ WBu[ta + 1])
                                 + __builtin_popcount(X.z ^ WBu[ta + 2])
                                 + __builtin_popcount(X.w ^ WBu[ta + 3]);
                    }
                }
            }
        }
    }

    if (lane < 56) {
        int w = lane;
        const int* wpa = wpop + (size_t)(og * 8 + 2 * wv) * 9;
        int pa[9], pb[9];
#pragma unroll
        for (int tp = 0; tp < 9; tp++) { pa[tp] = wpa[tp]; pb[tp] = wpa[tp + 9]; }
        float* oa = out + (((size_t)n * 256 + og * 8 + 2 * wv) * 56 + hb) * 56 + w;
        float* ob = oa + 56 * 56;
        bool edge_w = (w == 0) | (w == 55);
#pragma unroll
        for (int r = 0; r < HPT; r++) {
            int hh = hb + r;
            int va = 2304 - 2 * acca[r];
            int vb = 2304 - 2 * accb[r];
            if (edge_w | (hh == 0) | (hh == 55)) {
                int ca = 0, cb = 0;
#pragma unroll
                for (int dh = -1; dh <= 1; dh++)
#pragma unroll
                    for (int dw = -1; dw <= 1; dw++)
                        if ((unsigned)(hh + dh) >= 56u || (unsigned)(w + dw) >= 56u) {
                            int tap = (dh + 1) * 3 + (dw + 1);
                            ca += 256 - 2 * pa[tap];
                            cb += 256 - 2 * pb[tap];
                        }
                va -= ca; vb -= cb;
            }
            oa[(size_t)r * 56] = (float)va;
            ob[(size_t)r * 56] = (float)vb;
        }
    }
}

extern "C" void kernel_launch(void* const* d_in, const int* in_sizes, int n_in,
                              void* d_out, int out_size, void* d_ws, size_t ws_size,
                              hipStream_t stream) {
    const float* x    = (const float*)d_in[0];
    const float* wsrc = (const float*)d_in[1];
    float* out = (float*)d_out;

    uint32_t* xpad  = (uint32_t*)d_ws;                    // 3.44 MB
    uint32_t* wbits = xpad + XPAD_U32;                    // 18432 u32
    int*      wpop  = (int*)(wbits + 256 * 9 * 8);        // 2304 int

    hipMemsetAsync(xpad, 0, (size_t)XPAD_U32 * 4, stream);
    binw_kernel<<<256, 256, 0, stream>>>(wsrc, wbits, wpop);
    binx_kernel<<<784, 256, 0, stream>>>(x, xpad);
    conv_kernel<<<dim3(8, 32, N_BATCH), 256, 0, stream>>>(xpad, wbits, wpop, out);
}

// Round 6
// 368.856 us; speedup vs baseline: 1.2293x; 1.2293x over previous
//
#include <hip/hip_runtime.h>
#include <stdint.h>

#define N_BATCH 32
#define CHN     256
#define HW      56
#define HP      58
#define HPT     7

// xpad layout (uint4 "cells" of 4 u32 = 128 channel-bits):
//   cell(n, hp, h, wp) = ((n*58 + hp)*2 + h)*58 + wp,  h = channel-half
#define XPAD_CELLS (N_BATCH * HP * 2 * HP)   // 215,296 cells
#define XPAD_U32   (XPAD_CELLS * 4)

// ---------------- weight binarization via ballot ----------------------------
__global__ __launch_bounds__(256) void binw_kernel(const float* __restrict__ wsrc,
                                                   uint32_t* __restrict__ wbits,
                                                   int* __restrict__ wpop) {
    __shared__ int part[9][4];
    int o = blockIdx.x;
    int t = threadIdx.x;
    int lane = t & 63, wv = t >> 6;
    const float* p = wsrc + ((size_t)o * 256 + t) * 9;
    float v[9];
#pragma unroll
    for (int tap = 0; tap < 9; tap++) v[tap] = p[tap];
#pragma unroll
    for (int tap = 0; tap < 9; tap++) {
        unsigned long long m = __ballot(v[tap] > 0.0f);
        if (lane == 0) {
            wbits[(size_t)(o * 9 + tap) * 8 + 2 * wv]     = (uint32_t)m;
            wbits[(size_t)(o * 9 + tap) * 8 + 2 * wv + 1] = (uint32_t)(m >> 32);
            part[tap][wv] = __builtin_popcountll(m);
        }
    }
    __syncthreads();
    if (t < 9) wpop[o * 9 + t] = part[t][0] + part[t][1] + part[t][2] + part[t][3];
}

// ---------------- x binarization (chunked loads, low VGPR) ------------------
__global__ __launch_bounds__(256) void binx_kernel(const float* __restrict__ x,
                                                   uint32_t* __restrict__ xpad) {
    int t    = threadIdx.x;
    int lane = t & 63;
    int fw   = blockIdx.x * 4 + (t >> 6);   // flat wave id, 0..3135
    int k    = fw & 7;                      // word index (channels 32k..32k+31)
    int q    = (fw >> 3) * 64 + lane;       // quad id, 0..25087
    int n    = q / 784;
    int pq   = q - n * 784;                 // quad within plane

    const float4* src = (const float4*)x + ((size_t)(n * 256 + k * 32)) * 784 + pq;
    uint32_t b0 = 0, b1 = 0, b2 = 0, b3 = 0;
#pragma unroll
    for (int g = 0; g < 4; g++) {
        float4 v[8];
#pragma unroll
        for (int u = 0; u < 8; u++) v[u] = src[(size_t)(g * 8 + u) * 784];
#pragma unroll
        for (int u = 0; u < 8; u++) {
            int cc = g * 8 + u;
            b0 |= (v[u].x > 0.0f ? 1u : 0u) << cc;
            b1 |= (v[u].y > 0.0f ? 1u : 0u) << cc;
            b2 |= (v[u].z > 0.0f ? 1u : 0u) << cc;
            b3 |= (v[u].w > 0.0f ? 1u : 0u) << cc;
        }
    }
    int h  = pq / 14;
    int wq = pq - h * 14;
    int w0 = wq * 4;
    uint32_t cell = ((uint32_t)(n * HP + h + 1) * 2 + (k >> 2)) * HP + (w0 + 1);
    uint32_t* dst = xpad + (size_t)cell * 4 + (k & 3);
    dst[0] = b0; dst[4] = b1; dst[8] = b2; dst[12] = b3;
}

// ---------------- binary conv ----------------------------------------------
// grid (8 strips, 64 o-groups of 4, 32 n), block 256 = 4 waves, 1 o per wave.
// X strip (9 padded rows x 58 px x 2 halves = 1044 cells) staged in LDS via
// plain vector loads (no global_load_lds); weights in two half-channel passes
// so only 36 W words are live at a time.
__global__ __launch_bounds__(256) void conv_kernel(const uint32_t* __restrict__ xpad,
                                                   const uint32_t* __restrict__ wbits,
                                                   const int* __restrict__ wpop,
                                                   float* __restrict__ out) {
    __shared__ uint4 sx[1044];      // 16.7 KB

    int t    = threadIdx.x;
    int lane = t & 63;
    int wv   = t >> 6;
    int strip = blockIdx.x;
    int og    = blockIdx.y;
    int n     = blockIdx.z;
    int hb    = strip * HPT;
    int o     = __builtin_amdgcn_readfirstlane(og * 4 + wv);   // wave-uniform

    // stage X strip: 1044 contiguous cells, plain loads, uniform loop bound
    const uint4* xg = (const uint4*)xpad + (size_t)(n * HP + hb) * (2 * HP);
    for (int i = t; i < 1044; i += 256)
        sx[i] = xg[i];
    __syncthreads();

    int acc[HPT];
#pragma unroll
    for (int r = 0; r < HPT; r++) acc[r] = 0;

    const uint32_t* wa = wbits + (size_t)o * 72;   // wave-uniform
    const char* sxb = (const char*)sx + lane * 16; // one addr reg, imm offsets

#pragma unroll
    for (int h = 0; h < 2; h++) {
        uint32_t Wh[36];
#pragma unroll
        for (int tap = 0; tap < 9; tap++)
#pragma unroll
            for (int i = 0; i < 4; i++)
                Wh[tap * 4 + i] = wa[tap * 8 + h * 4 + i];
#pragma unroll
        for (int j = 0; j < HPT + 2; j++) {
            uint4 X0 = *(const uint4*)(sxb + ((j * 2 + h) * HP + 0) * 16);
            uint4 X1 = *(const uint4*)(sxb + ((j * 2 + h) * HP + 1) * 16);
            uint4 X2 = *(const uint4*)(sxb + ((j * 2 + h) * HP + 2) * 16);
#pragma unroll
            for (int dh = 0; dh < 3; dh++) {
                int r = j - dh;
                if (r >= 0 && r < HPT) {
#pragma unroll
                    for (int dw = 0; dw < 3; dw++) {
                        uint4 X = (dw == 0) ? X0 : (dw == 1) ? X1 : X2;
                        int ta = (dh * 3 + dw) * 4;
                        acc[r] += __builtin_popcount(X.x ^ Wh[ta + 0])
                                + __builtin_popcount(X.y ^ Wh[ta + 1])
                                + __builtin_popcount(X.z ^ Wh[ta + 2])
                                + __builtin_popcount(X.w ^ Wh[ta + 3]);
                    }
                }
            }
        }
    }

    if (lane < 56) {
        int w = lane;
        const int* wpa = wpop + (size_t)o * 9;
        int pa[9];
#pragma unroll
        for (int tp = 0; tp < 9; tp++) pa[tp] = wpa[tp];
        float* oa = out + (((size_t)n * 256 + o) * 56 + hb) * 56 + w;
        bool edge_w = (w == 0) | (w == 55);
#pragma unroll
        for (int r = 0; r < HPT; r++) {
            int hh = hb + r;
            int va = 2304 - 2 * acc[r];
            if (edge_w | (hh == 0) | (hh == 55)) {
                int ca = 0;
#pragma unroll
                for (int dh = -1; dh <= 1; dh++)
#pragma unroll
                    for (int dw = -1; dw <= 1; dw++)
                        if ((unsigned)(hh + dh) >= 56u || (unsigned)(w + dw) >= 56u)
                            ca += 256 - 2 * pa[(dh + 1) * 3 + (dw + 1)];
                va -= ca;
            }
            oa[(size_t)r * 56] = (float)va;
        }
    }
}

extern "C" void kernel_launch(void* const* d_in, const int* in_sizes, int n_in,
                              void* d_out, int out_size, void* d_ws, size_t ws_size,
                              hipStream_t stream) {
    const float* x    = (const float*)d_in[0];
    const float* wsrc = (const float*)d_in[1];
    float* out = (float*)d_out;

    uint32_t* xpad  = (uint32_t*)d_ws;                    // 3.44 MB
    uint32_t* wbits = xpad + XPAD_U32;                    // 18432 u32
    int*      wpop  = (int*)(wbits + 256 * 9 * 8);        // 2304 int

    hipMemsetAsync(xpad, 0, (size_t)XPAD_U32 * 4, stream);
    binw_kernel<<<256, 256, 0, stream>>>(wsrc, wbits, wpop);
    binx_kernel<<<784, 256, 0, stream>>>(x, xpad);
    conv_kernel<<<dim3(8, 64, N_BATCH), 256, 0, stream>>>(xpad, wbits, wpop, out);
}